// Round 9
// baseline (343.162 us; speedup 1.0000x reference)
//
#include <hip/hip_runtime.h>

#define LEAKY 0.2f
#define SCAN_BS 256

typedef __attribute__((ext_vector_type(8))) short bf16x8;
typedef __attribute__((ext_vector_type(4))) float f32x4;

__device__ __forceinline__ unsigned short f2bf(float f) {
    unsigned u = __float_as_uint(f);
    u += 0x7FFF + ((u >> 16) & 1);          // RTNE
    return (unsigned short)(u >> 16);
}
__device__ __forceinline__ float bf2f(unsigned short u) {
    return __uint_as_float((unsigned)u << 16);
}

// ---------------------------------------------------------------- zero fill
__global__ __launch_bounds__(256) void zero_kernel(int4* __restrict__ p, int n4) {
    int i = blockIdx.x * 256 + threadIdx.x;
    if (i < n4) p[i] = (int4){0, 0, 0, 0};
}

// ---------------------------------------------------------------- CSR build
// Pass 1: histogram whose atomic RETURN VALUE is the edge's rank in its row.
__global__ __launch_bounds__(256) void hist_rank_kernel(const int* __restrict__ row, int E,
                                                        int* __restrict__ deg,
                                                        int* __restrict__ rank) {
    int base = (blockIdx.x * 256 + threadIdx.x) * 4;
    if (base + 4 <= E) {
        int4 r = *reinterpret_cast<const int4*>(row + base);
        int4 k;
        k.x = atomicAdd(&deg[r.x], 1);
        k.y = atomicAdd(&deg[r.y], 1);
        k.z = atomicAdd(&deg[r.z], 1);
        k.w = atomicAdd(&deg[r.w], 1);
        *reinterpret_cast<int4*>(rank + base) = k;
    } else {
        for (int e = base; e < E; ++e) rank[e] = atomicAdd(&deg[row[e]], 1);
    }
}

__global__ __launch_bounds__(SCAN_BS) void bsum_kernel(const int* __restrict__ deg,
                                                       int* __restrict__ bsums, int n) {
    int i = blockIdx.x * SCAN_BS + threadIdx.x;
    int v = (i < n) ? deg[i] : 0;
    for (int off = 32; off; off >>= 1) v += __shfl_xor(v, off, 64);
    __shared__ int wsum[SCAN_BS / 64];
    int lane = threadIdx.x & 63, w = threadIdx.x >> 6;
    if (lane == 0) wsum[w] = v;
    __syncthreads();
    if (threadIdx.x == 0) {
        int s = 0;
#pragma unroll
        for (int j = 0; j < SCAN_BS / 64; ++j) s += wsum[j];
        bsums[blockIdx.x] = s;
    }
}

__global__ __launch_bounds__(1024) void scan_bsums_kernel(int* __restrict__ bsums, int nb) {
    __shared__ int sh[1024];
    int tid = threadIdx.x;
    int v = (tid < nb) ? bsums[tid] : 0;
    sh[tid] = v;
    __syncthreads();
    for (int off = 1; off < 1024; off <<= 1) {
        int u = (tid >= off) ? sh[tid - off] : 0;
        __syncthreads();
        sh[tid] += u;
        __syncthreads();
    }
    if (tid < nb) bsums[tid] = sh[tid] - v;  // exclusive
}

// scan + dinv fused (saves a launch)
__global__ __launch_bounds__(SCAN_BS) void rowptr_dinv_kernel(const int* __restrict__ deg,
                                                              const int* __restrict__ bsums_ex,
                                                              int* __restrict__ rowptr,
                                                              float* __restrict__ dinv, int n) {
    __shared__ int sh[SCAN_BS];
    int tid = threadIdx.x;
    int i = blockIdx.x * SCAN_BS + tid;
    int v = (i < n) ? deg[i] : 0;
    sh[tid] = v;
    __syncthreads();
    for (int off = 1; off < SCAN_BS; off <<= 1) {
        int u = (tid >= off) ? sh[tid - off] : 0;
        __syncthreads();
        sh[tid] += u;
        __syncthreads();
    }
    if (i <= n) rowptr[i] = sh[tid] - v + bsums_ex[blockIdx.x];
    if (i < n) dinv[i] = v > 0 ? rsqrtf((float)v) : 0.0f;
}

// Pass 2: atomic-free placement: p = rowptr[row[e]] + rank[e].
__global__ __launch_bounds__(256) void scatter_store_kernel(const int* __restrict__ row,
                                                            const int* __restrict__ col,
                                                            const int* __restrict__ rank, int E,
                                                            const int* __restrict__ rowptr,
                                                            int* __restrict__ cols_s) {
    int base = (blockIdx.x * 256 + threadIdx.x) * 4;
    if (base + 4 <= E) {
        int4 r = *reinterpret_cast<const int4*>(row + base);
        int4 c = *reinterpret_cast<const int4*>(col + base);
        int4 k = *reinterpret_cast<const int4*>(rank + base);
        int p0 = rowptr[r.x];
        int p1 = rowptr[r.y];
        int p2 = rowptr[r.z];
        int p3 = rowptr[r.w];
        cols_s[p0 + k.x] = c.x;
        cols_s[p1 + k.y] = c.y;
        cols_s[p2 + k.z] = c.z;
        cols_s[p3 + k.w] = c.w;
    } else {
        for (int e = base; e < E; ++e) cols_s[rowptr[row[e]] + rank[e]] = col[e];
    }
}

__global__ __launch_bounds__(256) void scale_kernel(const float* __restrict__ dinv,
                                                    const float* __restrict__ len,
                                                    float* __restrict__ scale, int n) {
    int i = blockIdx.x * 256 + threadIdx.x;
    if (i < n) scale[i] = dinv[i] * len[i];
}

// ---------------------------------------------------------------- fused aggregate+transform
// Each wave owns 16 nodes. Phase 1 (lane=dim): gather-aggregate each node's
// agg row + m row (agg .* h*len), convert to bf16, store into the wave's
// PRIVATE LDS tile (XOR-swizzled, no barrier needed: wave-local producer/
// consumer). Phase 2: read A/M MFMA fragments from LDS, 16 MFMA transform,
// bias+leaky+fused l2-norm epilogue. Kills the agg HBM round-trip and the
// duplicate h_bf read.
__global__ __launch_bounds__(256, 3) void agg_transform_kernel(
        const int* __restrict__ rowptr,
        const int* __restrict__ cols_s,
        const float* __restrict__ scale,
        const float* __restrict__ dinv,
        const unsigned short* __restrict__ h_bf,
        const float* __restrict__ len_in,
        const float* __restrict__ w1,
        const float* __restrict__ b1,
        const float* __restrict__ w2,
        const float* __restrict__ b2,
        float* __restrict__ out_norm,
        int ostride,
        float* __restrict__ len_out,
        unsigned short* __restrict__ hbf_out,
        int n_nodes) {
    __shared__ unsigned short ldsA[4][16][64];   // [wave][node][dim], swizzled
    __shared__ unsigned short ldsM[4][16][64];
    int lane = threadIdx.x & 63;
    int w = threadIdx.x >> 6;
    int wave = blockIdx.x * 4 + w;
    int n0 = wave * 16;
    if (n0 >= n_nodes) return;

    char* rowA0 = (char*)&ldsA[w][0][0];
    char* rowM0 = (char*)&ldsM[w][0][0];

    // ---------------- phase 1: aggregate 16 nodes (lane = dim)
#pragma unroll 1
    for (int ni = 0; ni < 16; ++ni) {
        int n = n0 + ni;
        float aggv = 0.0f, mv = 0.0f;
        if (n < n_nodes) {
            int nu = __builtin_amdgcn_readfirstlane(n);
            int s = rowptr[nu];
            int e = rowptr[nu + 1];
            float dn = dinv[nu];
            float acc0 = 0.0f, acc1 = 0.0f, acc2 = 0.0f, acc3 = 0.0f;
            int t = s;
            for (; t + 7 < e; t += 8) {
                int c[8];
                float ww[8];
#pragma unroll
                for (int j = 0; j < 8; ++j) c[j] = cols_s[t + j];
#pragma unroll
                for (int j = 0; j < 8; ++j) ww[j] = scale[c[j]];
                float hv[8];
#pragma unroll
                for (int j = 0; j < 8; ++j) hv[j] = bf2f(h_bf[((size_t)c[j] << 6) + lane]);
                acc0 = fmaf(ww[0], hv[0], acc0);
                acc1 = fmaf(ww[1], hv[1], acc1);
                acc2 = fmaf(ww[2], hv[2], acc2);
                acc3 = fmaf(ww[3], hv[3], acc3);
                acc0 = fmaf(ww[4], hv[4], acc0);
                acc1 = fmaf(ww[5], hv[5], acc1);
                acc2 = fmaf(ww[6], hv[6], acc2);
                acc3 = fmaf(ww[7], hv[7], acc3);
            }
            if (t + 3 < e) {
                int c0 = cols_s[t + 0];
                int c1 = cols_s[t + 1];
                int c2 = cols_s[t + 2];
                int c3 = cols_s[t + 3];
                float w0 = scale[c0];
                float w1_ = scale[c1];
                float w2_ = scale[c2];
                float w3 = scale[c3];
                acc0 = fmaf(w0, bf2f(h_bf[((size_t)c0 << 6) + lane]), acc0);
                acc1 = fmaf(w1_, bf2f(h_bf[((size_t)c1 << 6) + lane]), acc1);
                acc2 = fmaf(w2_, bf2f(h_bf[((size_t)c2 << 6) + lane]), acc2);
                acc3 = fmaf(w3, bf2f(h_bf[((size_t)c3 << 6) + lane]), acc3);
                t += 4;
            }
            for (; t < e; ++t) {
                int c0 = cols_s[t];
                acc0 = fmaf(scale[c0], bf2f(h_bf[((size_t)c0 << 6) + lane]), acc0);
            }
            aggv = dn * ((acc0 + acc1) + (acc2 + acc3));
            float lv = len_in ? len_in[nu] : 1.0f;
            float hown = bf2f(h_bf[((size_t)nu << 6) + lane]);
            mv = aggv * hown * lv;
        }
        // swizzled store: byte off = (dim*2) ^ ((node&7)<<4) within the node's row
        unsigned off = ((unsigned)(lane * 2)) ^ ((unsigned)(ni & 7) << 4);
        *(unsigned short*)(rowA0 + ni * 128 + off) = f2bf(aggv);
        *(unsigned short*)(rowM0 + ni * 128 + off) = f2bf(mv);
    }

    // ---------------- phase 2: MFMA transform
    int r16 = lane & 15;
    int g   = lane >> 4;

    bf16x8 w1f[2][4], w2f[2][4];
#pragma unroll
    for (int kt = 0; kt < 2; ++kt) {
#pragma unroll
        for (int dt = 0; dt < 4; ++dt) {
            const float* p1 = w1 + (kt * 32 + 8 * g) * 64 + dt * 16 + r16;
            const float* p2 = w2 + (kt * 32 + 8 * g) * 64 + dt * 16 + r16;
            bf16x8 f1, f2;
#pragma unroll
            for (int j = 0; j < 8; ++j) {
                f1[j] = (short)f2bf(p1[(size_t)j * 64]);
                f2[j] = (short)f2bf(p2[(size_t)j * 64]);
            }
            w1f[kt][dt] = f1;
            w2f[kt][dt] = f2;
        }
    }

    f32x4 acc1[4], acc2[4];
#pragma unroll
    for (int dt = 0; dt < 4; ++dt) {
        acc1[dt] = (f32x4){0.0f, 0.0f, 0.0f, 0.0f};
        acc2[dt] = (f32x4){0.0f, 0.0f, 0.0f, 0.0f};
    }

#pragma unroll
    for (int kt = 0; kt < 2; ++kt) {
        // A frag: node r16, dims kt*32+8g..+7 -> swizzled 16B block
        unsigned blk = (unsigned)((kt * 4 + g) ^ (r16 & 7)) << 4;
        bf16x8 af = *reinterpret_cast<const bf16x8*>(rowA0 + r16 * 128 + blk);
        bf16x8 mf = *reinterpret_cast<const bf16x8*>(rowM0 + r16 * 128 + blk);
#pragma unroll
        for (int dt = 0; dt < 4; ++dt) {
            acc1[dt] = __builtin_amdgcn_mfma_f32_16x16x32_bf16(af, w1f[kt][dt], acc1[dt], 0, 0, 0);
            acc2[dt] = __builtin_amdgcn_mfma_f32_16x16x32_bf16(mf, w2f[kt][dt], acc2[dt], 0, 0, 0);
        }
    }

    float b1v[4], b2v[4];
#pragma unroll
    for (int dt = 0; dt < 4; ++dt) {
        b1v[dt] = b1[dt * 16 + r16];
        b2v[dt] = b2[dt * 16 + r16];
    }
    float v[4][4];  // [dt][reg]
#pragma unroll
    for (int dt = 0; dt < 4; ++dt) {
#pragma unroll
        for (int reg = 0; reg < 4; ++reg) {
            float x1 = acc1[dt][reg] + b1v[dt];
            float x2 = acc2[dt][reg] + b2v[dt];
            x1 = x1 > 0.0f ? x1 : LEAKY * x1;
            x2 = x2 > 0.0f ? x2 : LEAKY * x2;
            v[dt][reg] = x1 + x2;
        }
    }
#pragma unroll
    for (int reg = 0; reg < 4; ++reg) {
        float sq = v[0][reg] * v[0][reg] + v[1][reg] * v[1][reg] +
                   v[2][reg] * v[2][reg] + v[3][reg] * v[3][reg];
        sq += __shfl_xor(sq, 1, 64);
        sq += __shfl_xor(sq, 2, 64);
        sq += __shfl_xor(sq, 4, 64);
        sq += __shfl_xor(sq, 8, 64);
        float m = fmaxf(sq, 1e-12f);
        float inv = rsqrtf(m);
        int orow = n0 + 4 * g + reg;
        if (orow < n_nodes) {
#pragma unroll
            for (int dt = 0; dt < 4; ++dt) {
                float nv = v[dt][reg] * inv;
                out_norm[(size_t)orow * ostride + dt * 16 + r16] = nv;
                hbf_out[((size_t)orow << 6) + dt * 16 + r16] = f2bf(nv);
            }
            if (r16 == reg) len_out[orow] = sqrtf(m);
        }
    }
}

// ---------------------------------------------------------------- copy x -> slot 0 (+ bf16 table)
__global__ __launch_bounds__(256) void copyx_kernel(const float* __restrict__ x,
                                                    float* __restrict__ out,
                                                    unsigned short* __restrict__ x_bf,
                                                    int n_nodes, int nslots) {
    int t = blockIdx.x * 256 + threadIdx.x;
    int total = n_nodes * 16;                 // 16 float4 per node row
    if (t >= total) return;
    int node = t >> 4;
    int j = t & 15;
    float4 v = reinterpret_cast<const float4*>(x)[(size_t)node * 16 + j];
    reinterpret_cast<float4*>(out)[(size_t)node * (nslots * 16) + j] = v;
    ushort4 b;
    b.x = f2bf(v.x); b.y = f2bf(v.y); b.z = f2bf(v.z); b.w = f2bf(v.w);
    reinterpret_cast<ushort4*>(x_bf)[(size_t)node * 16 + j] = b;
}

// ---------------------------------------------------------------- launch
extern "C" void kernel_launch(void* const* d_in, const int* in_sizes, int n_in,
                              void* d_out, int out_size, void* d_ws, size_t ws_size,
                              hipStream_t stream) {
    const float* x  = (const float*)d_in[0];
    const int*  edge = (const int*)d_in[1];
    const float* W1 = (const float*)d_in[2];
    const float* b1 = (const float*)d_in[3];
    const float* W2 = (const float*)d_in[4];
    const float* b2 = (const float*)d_in[5];

    const int N = in_sizes[0] / 64;
    const int E = in_sizes[1] / 2;
    const int K = in_sizes[2] / 4096;
    const int nslots = K + 1;
    const int ostride = nslots * 64;

    const int* row = edge;
    const int* col = edge + E;
    float* out = (float*)d_out;

    char* ws = (char*)d_ws;
    size_t off = 0;
    auto carve = [&](size_t bytes) -> void* {
        void* p = ws + off;
        off = (off + bytes + 255) & ~(size_t)255;
        return p;
    };
    int*   deg     = (int*)  carve((size_t)N * 4);
    int*   rowptr  = (int*)  carve((size_t)(N + 1) * 4);
    float* dinv    = (float*)carve((size_t)N * 4);
    float* scale   = (float*)carve((size_t)N * 4);
    float* len     = (float*)carve((size_t)N * 4);
    int*   rank    = (int*)  carve((size_t)E * 4);
    int*   cols_s  = (int*)  carve((size_t)E * 4);
    unsigned short* hbfA = (unsigned short*)carve((size_t)N * 64 * 2);
    unsigned short* hbfB = (unsigned short*)carve((size_t)N * 64 * 2);
    int*   bsums   = (int*)  carve(2048 * 4);
    (void)ws_size;

    const int n4 = (N + 3) / 4;
    zero_kernel<<<(n4 + 255) / 256, 256, 0, stream>>>((int4*)deg, n4);

    const int eblk4 = (E + 256 * 4 - 1) / (256 * 4);
    hist_rank_kernel<<<eblk4, 256, 0, stream>>>(row, E, deg, rank);

    const int nb = (N + 1 + SCAN_BS - 1) / SCAN_BS;
    bsum_kernel<<<nb, SCAN_BS, 0, stream>>>(deg, bsums, N);
    scan_bsums_kernel<<<1, 1024, 0, stream>>>(bsums, nb);
    rowptr_dinv_kernel<<<nb, SCAN_BS, 0, stream>>>(deg, bsums, rowptr, dinv, N);

    scatter_store_kernel<<<eblk4, 256, 0, stream>>>(row, col, rank, E, rowptr, cols_s);

    copyx_kernel<<<(N * 16 + 255) / 256, 256, 0, stream>>>(x, out, hbfA, N, nslots);

    const int waves_needed = (N + 15) / 16;
    const int ftblocks = (waves_needed + 3) / 4;
    const int nblk256 = (N + 255) / 256;

    unsigned short* hin = hbfA;
    unsigned short* hout = hbfB;
    for (int i = 0; i < K; ++i) {
        const float* len_in;
        const float* sc;
        if (i == 0) {
            len_in = nullptr; sc = dinv;
        } else {
            len_in = len;
            scale_kernel<<<nblk256, 256, 0, stream>>>(dinv, len, scale, N);
            sc = scale;
        }
        agg_transform_kernel<<<ftblocks, 256, 0, stream>>>(rowptr, cols_s, sc, dinv,
                                                           hin, len_in,
                                                           W1 + (size_t)i * 4096,
                                                           b1 + (size_t)i * 64,
                                                           W2 + (size_t)i * 4096,
                                                           b2 + (size_t)i * 64,
                                                           out + (size_t)(i + 1) * 64,
                                                           ostride, len, hout, N);
        unsigned short* tmp = hin; hin = hout; hout = tmp;
    }
}

// Round 10
// 273.831 us; speedup vs baseline: 1.2532x; 1.2532x over previous
//
#include <hip/hip_runtime.h>

#define LEAKY 0.2f
#define SCAN_BS 256

typedef __attribute__((ext_vector_type(8))) short bf16x8;
typedef __attribute__((ext_vector_type(4))) float f32x4;

__device__ __forceinline__ unsigned short f2bf(float f) {
    unsigned u = __float_as_uint(f);
    u += 0x7FFF + ((u >> 16) & 1);          // RTNE
    return (unsigned short)(u >> 16);
}
__device__ __forceinline__ float bf2f(unsigned short u) {
    return __uint_as_float((unsigned)u << 16);
}

// ---------------------------------------------------------------- zero fill
__global__ __launch_bounds__(256) void zero_kernel(int4* __restrict__ p, int n4) {
    int i = blockIdx.x * 256 + threadIdx.x;
    if (i < n4) p[i] = (int4){0, 0, 0, 0};
}

// ---------------------------------------------------------------- CSR build
// Pass 1: histogram whose atomic RETURN VALUE is the edge's rank in its row.
__global__ __launch_bounds__(256) void hist_rank_kernel(const int* __restrict__ row, int E,
                                                        int* __restrict__ deg,
                                                        int* __restrict__ rank) {
    int base = (blockIdx.x * 256 + threadIdx.x) * 4;
    if (base + 4 <= E) {
        int4 r = *reinterpret_cast<const int4*>(row + base);
        int4 k;
        k.x = atomicAdd(&deg[r.x], 1);
        k.y = atomicAdd(&deg[r.y], 1);
        k.z = atomicAdd(&deg[r.z], 1);
        k.w = atomicAdd(&deg[r.w], 1);
        *reinterpret_cast<int4*>(rank + base) = k;
    } else {
        for (int e = base; e < E; ++e) rank[e] = atomicAdd(&deg[row[e]], 1);
    }
}

__global__ __launch_bounds__(SCAN_BS) void bsum_kernel(const int* __restrict__ deg,
                                                       int* __restrict__ bsums, int n) {
    int i = blockIdx.x * SCAN_BS + threadIdx.x;
    int v = (i < n) ? deg[i] : 0;
    for (int off = 32; off; off >>= 1) v += __shfl_xor(v, off, 64);
    __shared__ int wsum[SCAN_BS / 64];
    int lane = threadIdx.x & 63, w = threadIdx.x >> 6;
    if (lane == 0) wsum[w] = v;
    __syncthreads();
    if (threadIdx.x == 0) {
        int s = 0;
#pragma unroll
        for (int j = 0; j < SCAN_BS / 64; ++j) s += wsum[j];
        bsums[blockIdx.x] = s;
    }
}

__global__ __launch_bounds__(1024) void scan_bsums_kernel(int* __restrict__ bsums, int nb) {
    __shared__ int sh[1024];
    int tid = threadIdx.x;
    int v = (tid < nb) ? bsums[tid] : 0;
    sh[tid] = v;
    __syncthreads();
    for (int off = 1; off < 1024; off <<= 1) {
        int u = (tid >= off) ? sh[tid - off] : 0;
        __syncthreads();
        sh[tid] += u;
        __syncthreads();
    }
    if (tid < nb) bsums[tid] = sh[tid] - v;  // exclusive
}

// scan + dinv fused (saves a launch)
__global__ __launch_bounds__(SCAN_BS) void rowptr_dinv_kernel(const int* __restrict__ deg,
                                                              const int* __restrict__ bsums_ex,
                                                              int* __restrict__ rowptr,
                                                              float* __restrict__ dinv, int n) {
    __shared__ int sh[SCAN_BS];
    int tid = threadIdx.x;
    int i = blockIdx.x * SCAN_BS + tid;
    int v = (i < n) ? deg[i] : 0;
    sh[tid] = v;
    __syncthreads();
    for (int off = 1; off < SCAN_BS; off <<= 1) {
        int u = (tid >= off) ? sh[tid - off] : 0;
        __syncthreads();
        sh[tid] += u;
        __syncthreads();
    }
    if (i <= n) rowptr[i] = sh[tid] - v + bsums_ex[blockIdx.x];
    if (i < n) dinv[i] = v > 0 ? rsqrtf((float)v) : 0.0f;
}

// Pass 2: atomic-free placement: p = rowptr[row[e]] + rank[e].
__global__ __launch_bounds__(256) void scatter_store_kernel(const int* __restrict__ row,
                                                            const int* __restrict__ col,
                                                            const int* __restrict__ rank, int E,
                                                            const int* __restrict__ rowptr,
                                                            int* __restrict__ cols_s) {
    int base = (blockIdx.x * 256 + threadIdx.x) * 4;
    if (base + 4 <= E) {
        int4 r = *reinterpret_cast<const int4*>(row + base);
        int4 c = *reinterpret_cast<const int4*>(col + base);
        int4 k = *reinterpret_cast<const int4*>(rank + base);
        int p0 = rowptr[r.x];
        int p1 = rowptr[r.y];
        int p2 = rowptr[r.z];
        int p3 = rowptr[r.w];
        cols_s[p0 + k.x] = c.x;
        cols_s[p1 + k.y] = c.y;
        cols_s[p2 + k.z] = c.z;
        cols_s[p3 + k.w] = c.w;
    } else {
        for (int e = base; e < E; ++e) cols_s[rowptr[row[e]] + rank[e]] = col[e];
    }
}

__global__ __launch_bounds__(256) void scale_kernel(const float* __restrict__ dinv,
                                                    const float* __restrict__ len,
                                                    float* __restrict__ scale, int n) {
    int i = blockIdx.x * 256 + threadIdx.x;
    if (i < n) scale[i] = dinv[i] * len[i];
}

// ---------------------------------------------------------------- aggregate
// wave per node; lanes = 8 edge-slots x 8 dim-slots. Each lane loads a 16B
// bf16x8 chunk of its edge's row -> ONE load instruction fetches 8 whole rows;
// two batches in flight = 16 edges/round (avg deg 12.8 -> ~1 dependent round).
// Reduce over edge-slots via 3 shfl_xor; lanes 0-7 store the bf16 agg row.
__global__ __launch_bounds__(256) void aggregate_kernel(const int* __restrict__ rowptr,
                                                        const int* __restrict__ cols_s,
                                                        const float* __restrict__ scale,
                                                        const float* __restrict__ dinv,
                                                        const unsigned short* __restrict__ h_bf,
                                                        unsigned short* __restrict__ agg_bf,
                                                        int n_nodes) {
    int lane = threadIdx.x & 63;
    int n = (blockIdx.x * blockDim.x + threadIdx.x) >> 6;
    if (n >= n_nodes) return;
    int nu = __builtin_amdgcn_readfirstlane(n);
    int s = rowptr[nu];
    int e = rowptr[nu + 1];
    int eg = lane >> 3;          // edge slot 0..7
    int dsl = lane & 7;          // dim slot: dims dsl*8 .. dsl*8+7

    float accA[8] = {0, 0, 0, 0, 0, 0, 0, 0};
    float accB[8] = {0, 0, 0, 0, 0, 0, 0, 0};
    for (int t = s; t < e; t += 16) {
        int i0 = t + eg;
        int i1 = t + 8 + eg;
        bool v0 = i0 < e;
        bool v1 = i1 < e;
        int c0 = cols_s[v0 ? i0 : (e - 1)];
        int c1 = cols_s[v1 ? i1 : (e - 1)];
        float w0 = v0 ? scale[c0] : 0.0f;
        float w1 = v1 ? scale[c1] : 0.0f;
        bf16x8 h0 = *reinterpret_cast<const bf16x8*>(h_bf + ((size_t)c0 << 6) + dsl * 8);
        bf16x8 h1 = *reinterpret_cast<const bf16x8*>(h_bf + ((size_t)c1 << 6) + dsl * 8);
#pragma unroll
        for (int j = 0; j < 8; ++j) accA[j] = fmaf(w0, bf2f((unsigned short)h0[j]), accA[j]);
#pragma unroll
        for (int j = 0; j < 8; ++j) accB[j] = fmaf(w1, bf2f((unsigned short)h1[j]), accB[j]);
    }
    float dn = dinv[nu];
#pragma unroll
    for (int j = 0; j < 8; ++j) {
        float a = accA[j] + accB[j];
        a += __shfl_xor(a, 8, 64);
        a += __shfl_xor(a, 16, 64);
        a += __shfl_xor(a, 32, 64);
        accA[j] = a * dn;
    }
    if (lane < 8) {
        bf16x8 o;
#pragma unroll
        for (int j = 0; j < 8; ++j) o[j] = (short)f2bf(accA[j]);
        *reinterpret_cast<bf16x8*>(agg_bf + ((size_t)nu << 6) + lane * 8) = o;
    }
}

// ---------------------------------------------------------------- transform (MFMA)
// One wave = 16-node x 64-dim output tile. C1 = A*W1, C2 = M*W2 with
// A = agg tile (bf16), M = agg .* (h_bf*len), via v_mfma_f32_16x16x32_bf16.
// Epilogue: bias + leaky + fused l2-norm; writes fp32 out row + bf16 h row.
__global__ __launch_bounds__(256, 3) void transform_kernel(const unsigned short* __restrict__ h_bf,
                                                           const float* __restrict__ len_in,
                                                           const unsigned short* __restrict__ agg_bf,
                                                           const float* __restrict__ w1,
                                                           const float* __restrict__ b1,
                                                           const float* __restrict__ w2,
                                                           const float* __restrict__ b2,
                                                           float* __restrict__ out_norm,
                                                           int ostride,
                                                           float* __restrict__ len_out,
                                                           unsigned short* __restrict__ hbf_out,
                                                           int n_nodes) {
    int lane = threadIdx.x & 63;
    int wave = (blockIdx.x * blockDim.x + threadIdx.x) >> 6;
    int n0 = wave * 16;
    if (n0 >= n_nodes) return;

    int r16 = lane & 15;   // A row / B,C col within tile
    int g   = lane >> 4;   // k-group

    bf16x8 w1f[2][4], w2f[2][4];
#pragma unroll
    for (int kt = 0; kt < 2; ++kt) {
#pragma unroll
        for (int dt = 0; dt < 4; ++dt) {
            const float* p1 = w1 + (kt * 32 + 8 * g) * 64 + dt * 16 + r16;
            const float* p2 = w2 + (kt * 32 + 8 * g) * 64 + dt * 16 + r16;
            bf16x8 f1, f2;
#pragma unroll
            for (int j = 0; j < 8; ++j) {
                f1[j] = (short)f2bf(p1[(size_t)j * 64]);
                f2[j] = (short)f2bf(p2[(size_t)j * 64]);
            }
            w1f[kt][dt] = f1;
            w2f[kt][dt] = f2;
        }
    }

    int row = n0 + r16;
    if (row >= n_nodes) row = n_nodes - 1;          // clamp for tail tile
    float lv = len_in ? len_in[row] : 1.0f;

    f32x4 acc1[4], acc2[4];
#pragma unroll
    for (int dt = 0; dt < 4; ++dt) {
        acc1[dt] = (f32x4){0.0f, 0.0f, 0.0f, 0.0f};
        acc2[dt] = (f32x4){0.0f, 0.0f, 0.0f, 0.0f};
    }

#pragma unroll
    for (int kt = 0; kt < 2; ++kt) {
        const unsigned short* ap = agg_bf + ((size_t)row << 6) + kt * 32 + 8 * g;
        const unsigned short* hp = h_bf + ((size_t)row << 6) + kt * 32 + 8 * g;
        bf16x8 af = *reinterpret_cast<const bf16x8*>(ap);
        bf16x8 h8 = *reinterpret_cast<const bf16x8*>(hp);
        bf16x8 mf;
#pragma unroll
        for (int j = 0; j < 8; ++j) {
            mf[j] = (short)f2bf(bf2f((unsigned short)af[j]) * bf2f((unsigned short)h8[j]) * lv);
        }
#pragma unroll
        for (int dt = 0; dt < 4; ++dt) {
            acc1[dt] = __builtin_amdgcn_mfma_f32_16x16x32_bf16(af, w1f[kt][dt], acc1[dt], 0, 0, 0);
            acc2[dt] = __builtin_amdgcn_mfma_f32_16x16x32_bf16(mf, w2f[kt][dt], acc2[dt], 0, 0, 0);
        }
    }

    float b1v[4], b2v[4];
#pragma unroll
    for (int dt = 0; dt < 4; ++dt) {
        b1v[dt] = b1[dt * 16 + r16];
        b2v[dt] = b2[dt * 16 + r16];
    }
    float v[4][4];  // [dt][reg]
#pragma unroll
    for (int dt = 0; dt < 4; ++dt) {
#pragma unroll
        for (int reg = 0; reg < 4; ++reg) {
            float x1 = acc1[dt][reg] + b1v[dt];
            float x2 = acc2[dt][reg] + b2v[dt];
            x1 = x1 > 0.0f ? x1 : LEAKY * x1;
            x2 = x2 > 0.0f ? x2 : LEAKY * x2;
            v[dt][reg] = x1 + x2;
        }
    }
#pragma unroll
    for (int reg = 0; reg < 4; ++reg) {
        float sq = v[0][reg] * v[0][reg] + v[1][reg] * v[1][reg] +
                   v[2][reg] * v[2][reg] + v[3][reg] * v[3][reg];
        sq += __shfl_xor(sq, 1, 64);
        sq += __shfl_xor(sq, 2, 64);
        sq += __shfl_xor(sq, 4, 64);
        sq += __shfl_xor(sq, 8, 64);
        float m = fmaxf(sq, 1e-12f);
        float inv = rsqrtf(m);
        int orow = n0 + 4 * g + reg;
        if (orow < n_nodes) {
#pragma unroll
            for (int dt = 0; dt < 4; ++dt) {
                float nv = v[dt][reg] * inv;
                out_norm[(size_t)orow * ostride + dt * 16 + r16] = nv;
                hbf_out[((size_t)orow << 6) + dt * 16 + r16] = f2bf(nv);
            }
            if (r16 == reg) len_out[orow] = sqrtf(m);
        }
    }
}

// ---------------------------------------------------------------- copy x -> slot 0 (+ bf16 table)
__global__ __launch_bounds__(256) void copyx_kernel(const float* __restrict__ x,
                                                    float* __restrict__ out,
                                                    unsigned short* __restrict__ x_bf,
                                                    int n_nodes, int nslots) {
    int t = blockIdx.x * 256 + threadIdx.x;
    int total = n_nodes * 16;                 // 16 float4 per node row
    if (t >= total) return;
    int node = t >> 4;
    int j = t & 15;
    float4 v = reinterpret_cast<const float4*>(x)[(size_t)node * 16 + j];
    reinterpret_cast<float4*>(out)[(size_t)node * (nslots * 16) + j] = v;
    ushort4 b;
    b.x = f2bf(v.x); b.y = f2bf(v.y); b.z = f2bf(v.z); b.w = f2bf(v.w);
    reinterpret_cast<ushort4*>(x_bf)[(size_t)node * 16 + j] = b;
}

// ---------------------------------------------------------------- launch
extern "C" void kernel_launch(void* const* d_in, const int* in_sizes, int n_in,
                              void* d_out, int out_size, void* d_ws, size_t ws_size,
                              hipStream_t stream) {
    const float* x  = (const float*)d_in[0];
    const int*  edge = (const int*)d_in[1];
    const float* W1 = (const float*)d_in[2];
    const float* b1 = (const float*)d_in[3];
    const float* W2 = (const float*)d_in[4];
    const float* b2 = (const float*)d_in[5];

    const int N = in_sizes[0] / 64;
    const int E = in_sizes[1] / 2;
    const int K = in_sizes[2] / 4096;
    const int nslots = K + 1;
    const int ostride = nslots * 64;

    const int* row = edge;
    const int* col = edge + E;
    float* out = (float*)d_out;

    char* ws = (char*)d_ws;
    size_t off = 0;
    auto carve = [&](size_t bytes) -> void* {
        void* p = ws + off;
        off = (off + bytes + 255) & ~(size_t)255;
        return p;
    };
    int*   deg     = (int*)  carve((size_t)N * 4);
    int*   rowptr  = (int*)  carve((size_t)(N + 1) * 4);
    float* dinv    = (float*)carve((size_t)N * 4);
    float* scale   = (float*)carve((size_t)N * 4);
    float* len     = (float*)carve((size_t)N * 4);
    int*   rank    = (int*)  carve((size_t)E * 4);
    int*   cols_s  = (int*)  carve((size_t)E * 4);
    unsigned short* agg_bf = (unsigned short*)carve((size_t)N * 64 * 2);
    unsigned short* hbfA = (unsigned short*)carve((size_t)N * 64 * 2);
    unsigned short* hbfB = (unsigned short*)carve((size_t)N * 64 * 2);
    int*   bsums   = (int*)  carve(2048 * 4);
    (void)ws_size;

    const int n4 = (N + 3) / 4;
    zero_kernel<<<(n4 + 255) / 256, 256, 0, stream>>>((int4*)deg, n4);

    const int eblk4 = (E + 256 * 4 - 1) / (256 * 4);
    hist_rank_kernel<<<eblk4, 256, 0, stream>>>(row, E, deg, rank);

    const int nb = (N + 1 + SCAN_BS - 1) / SCAN_BS;
    bsum_kernel<<<nb, SCAN_BS, 0, stream>>>(deg, bsums, N);
    scan_bsums_kernel<<<1, 1024, 0, stream>>>(bsums, nb);
    rowptr_dinv_kernel<<<nb, SCAN_BS, 0, stream>>>(deg, bsums, rowptr, dinv, N);

    scatter_store_kernel<<<eblk4, 256, 0, stream>>>(row, col, rank, E, rowptr, cols_s);

    copyx_kernel<<<(N * 16 + 255) / 256, 256, 0, stream>>>(x, out, hbfA, N, nslots);

    const int waves_needed = (N + 15) / 16;
    const int tblocks = (waves_needed + 3) / 4;
    const int nblk256 = (N + 255) / 256;

    unsigned short* hin = hbfA;
    unsigned short* hout = hbfB;
    for (int i = 0; i < K; ++i) {
        const float* len_in;
        const float* sc;
        if (i == 0) {
            len_in = nullptr; sc = dinv;
        } else {
            len_in = len;
            scale_kernel<<<nblk256, 256, 0, stream>>>(dinv, len, scale, N);
            sc = scale;
        }
        aggregate_kernel<<<(N * 64 + 255) / 256, 256, 0, stream>>>(rowptr, cols_s, sc, dinv,
                                                                   hin, agg_bf, N);
        transform_kernel<<<tblocks, 256, 0, stream>>>(hin, len_in, agg_bf,
                                                      W1 + (size_t)i * 4096,
                                                      b1 + (size_t)i * 64,
                                                      W2 + (size_t)i * 4096,
                                                      b2 + (size_t)i * 64,
                                                      out + (size_t)(i + 1) * 64,
                                                      ostride, len, hout, N);
        unsigned short* tmp = hin; hin = hout; hout = tmp;
    }
}

// Round 12
// 257.564 us; speedup vs baseline: 1.3323x; 1.0632x over previous
//
#include <hip/hip_runtime.h>

#define LEAKY 0.2f
#define SCAN_BS 256

typedef __attribute__((ext_vector_type(8))) short bf16x8;
typedef __attribute__((ext_vector_type(4))) float f32x4;

__device__ __forceinline__ unsigned short f2bf(float f) {
    unsigned u = __float_as_uint(f);
    u += 0x7FFF + ((u >> 16) & 1);          // RTNE
    return (unsigned short)(u >> 16);
}
__device__ __forceinline__ float bf2f(unsigned short u) {
    return __uint_as_float((unsigned)u << 16);
}

// ---------------------------------------------------------------- W fragment prep
// Pre-convert W1/W2 (f32, [K][64][64]) into bf16 MFMA B-fragments laid out so a
// transform wave loads each fragment with ONE coalesced 16B/lane instruction.
// Layout: frag[((L*2+m)*2+kt)*4+dt][lane] = bf16x8 { W[L,m][kt*32+8g+j][dt*16+r16] }
__global__ __launch_bounds__(256) void wprep_kernel(const float* __restrict__ w1,
                                                    const float* __restrict__ w2,
                                                    unsigned short* __restrict__ wfrag,
                                                    int total) {
    int t = blockIdx.x * 256 + threadIdx.x;
    if (t >= total) return;                 // total = K*2*2*4*64
    int lane = t & 63;
    int dt = (t >> 6) & 3;
    int kt = (t >> 8) & 1;
    int m  = (t >> 9) & 1;
    int L  = t >> 10;
    int r16 = lane & 15, g = lane >> 4;
    const float* wsrc = (m == 0 ? w1 : w2) + (size_t)L * 4096;
    const float* p = wsrc + (kt * 32 + 8 * g) * 64 + dt * 16 + r16;
    bf16x8 f;
#pragma unroll
    for (int j = 0; j < 8; ++j) f[j] = (short)f2bf(p[(size_t)j * 64]);
    *reinterpret_cast<bf16x8*>(wfrag + (size_t)t * 8) = f;
}

// ---------------------------------------------------------------- CSR build
// Pass 1: histogram whose atomic RETURN VALUE is the edge's rank in its row.
__global__ __launch_bounds__(256) void hist_rank_kernel(const int* __restrict__ row, int E,
                                                        int* __restrict__ deg,
                                                        int* __restrict__ rank) {
    int base = (blockIdx.x * 256 + threadIdx.x) * 4;
    if (base + 4 <= E) {
        int4 r = *reinterpret_cast<const int4*>(row + base);
        int4 k;
        k.x = atomicAdd(&deg[r.x], 1);
        k.y = atomicAdd(&deg[r.y], 1);
        k.z = atomicAdd(&deg[r.z], 1);
        k.w = atomicAdd(&deg[r.w], 1);
        *reinterpret_cast<int4*>(rank + base) = k;
    } else {
        for (int e = base; e < E; ++e) rank[e] = atomicAdd(&deg[row[e]], 1);
    }
}

__global__ __launch_bounds__(SCAN_BS) void bsum_kernel(const int* __restrict__ deg,
                                                       int* __restrict__ bsums, int n) {
    int i = blockIdx.x * SCAN_BS + threadIdx.x;
    int v = (i < n) ? deg[i] : 0;
    for (int off = 32; off; off >>= 1) v += __shfl_xor(v, off, 64);
    __shared__ int wsum[SCAN_BS / 64];
    int lane = threadIdx.x & 63, w = threadIdx.x >> 6;
    if (lane == 0) wsum[w] = v;
    __syncthreads();
    if (threadIdx.x == 0) {
        int s = 0;
#pragma unroll
        for (int j = 0; j < SCAN_BS / 64; ++j) s += wsum[j];
        bsums[blockIdx.x] = s;
    }
}

__global__ __launch_bounds__(1024) void scan_bsums_kernel(int* __restrict__ bsums, int nb) {
    __shared__ int sh[1024];
    int tid = threadIdx.x;
    int v = (tid < nb) ? bsums[tid] : 0;
    sh[tid] = v;
    __syncthreads();
    for (int off = 1; off < 1024; off <<= 1) {
        int u = (tid >= off) ? sh[tid - off] : 0;
        __syncthreads();
        sh[tid] += u;
        __syncthreads();
    }
    if (tid < nb) bsums[tid] = sh[tid] - v;  // exclusive
}

// scan + dinv fused
__global__ __launch_bounds__(SCAN_BS) void rowptr_dinv_kernel(const int* __restrict__ deg,
                                                              const int* __restrict__ bsums_ex,
                                                              int* __restrict__ rowptr,
                                                              float* __restrict__ dinv, int n) {
    __shared__ int sh[SCAN_BS];
    int tid = threadIdx.x;
    int i = blockIdx.x * SCAN_BS + tid;
    int v = (i < n) ? deg[i] : 0;
    sh[tid] = v;
    __syncthreads();
    for (int off = 1; off < SCAN_BS; off <<= 1) {
        int u = (tid >= off) ? sh[tid - off] : 0;
        __syncthreads();
        sh[tid] += u;
        __syncthreads();
    }
    if (i <= n) rowptr[i] = sh[tid] - v + bsums_ex[blockIdx.x];
    if (i < n) dinv[i] = v > 0 ? rsqrtf((float)v) : 0.0f;
}

// Pass 2: atomic-free placement: p = rowptr[row[e]] + rank[e].
__global__ __launch_bounds__(256) void scatter_store_kernel(const int* __restrict__ row,
                                                            const int* __restrict__ col,
                                                            const int* __restrict__ rank, int E,
                                                            const int* __restrict__ rowptr,
                                                            int* __restrict__ cols_s) {
    int base = (blockIdx.x * 256 + threadIdx.x) * 4;
    if (base + 4 <= E) {
        int4 r = *reinterpret_cast<const int4*>(row + base);
        int4 c = *reinterpret_cast<const int4*>(col + base);
        int4 k = *reinterpret_cast<const int4*>(rank + base);
        int p0 = rowptr[r.x];
        int p1 = rowptr[r.y];
        int p2 = rowptr[r.z];
        int p3 = rowptr[r.w];
        cols_s[p0 + k.x] = c.x;
        cols_s[p1 + k.y] = c.y;
        cols_s[p2 + k.z] = c.z;
        cols_s[p3 + k.w] = c.w;
    } else {
        for (int e = base; e < E; ++e) cols_s[rowptr[row[e]] + rank[e]] = col[e];
    }
}

// ---------------------------------------------------------------- aggregate
// wave per node; lanes = 8 edge-slots x 8 dim-slots; one 16B bf16x8 load per
// lane fetches 8 whole rows per instruction; 16 edges in flight per round.
__global__ __launch_bounds__(256) void aggregate_kernel(const int* __restrict__ rowptr,
                                                        const int* __restrict__ cols_s,
                                                        const float* __restrict__ scale,
                                                        const float* __restrict__ dinv,
                                                        const unsigned short* __restrict__ h_bf,
                                                        unsigned short* __restrict__ agg_bf,
                                                        int n_nodes) {
    int lane = threadIdx.x & 63;
    int n = (blockIdx.x * blockDim.x + threadIdx.x) >> 6;
    if (n >= n_nodes) return;
    int nu = __builtin_amdgcn_readfirstlane(n);
    int s = rowptr[nu];
    int e = rowptr[nu + 1];
    int eg = lane >> 3;          // edge slot 0..7
    int dsl = lane & 7;          // dim slot: dims dsl*8 .. dsl*8+7

    float accA[8] = {0, 0, 0, 0, 0, 0, 0, 0};
    float accB[8] = {0, 0, 0, 0, 0, 0, 0, 0};
    for (int t = s; t < e; t += 16) {
        int i0 = t + eg;
        int i1 = t + 8 + eg;
        bool v0 = i0 < e;
        bool v1 = i1 < e;
        int c0 = cols_s[v0 ? i0 : (e - 1)];
        int c1 = cols_s[v1 ? i1 : (e - 1)];
        float w0 = v0 ? scale[c0] : 0.0f;
        float w1 = v1 ? scale[c1] : 0.0f;
        bf16x8 h0 = *reinterpret_cast<const bf16x8*>(h_bf + ((size_t)c0 << 6) + dsl * 8);
        bf16x8 h1 = *reinterpret_cast<const bf16x8*>(h_bf + ((size_t)c1 << 6) + dsl * 8);
#pragma unroll
        for (int j = 0; j < 8; ++j) accA[j] = fmaf(w0, bf2f((unsigned short)h0[j]), accA[j]);
#pragma unroll
        for (int j = 0; j < 8; ++j) accB[j] = fmaf(w1, bf2f((unsigned short)h1[j]), accB[j]);
    }
    float dn = dinv[nu];
#pragma unroll
    for (int j = 0; j < 8; ++j) {
        float a = accA[j] + accB[j];
        a += __shfl_xor(a, 8, 64);
        a += __shfl_xor(a, 16, 64);
        a += __shfl_xor(a, 32, 64);
        accA[j] = a * dn;
    }
    if (lane < 8) {
        bf16x8 o;
#pragma unroll
        for (int j = 0; j < 8; ++j) o[j] = (short)f2bf(accA[j]);
        *reinterpret_cast<bf16x8*>(agg_bf + ((size_t)nu << 6) + lane * 8) = o;
    }
}

// ---------------------------------------------------------------- transform (MFMA)
// One wave = 16-node x 64-dim tile. Weights come pre-converted/fragment-ordered
// from wprep (16 coalesced 16B loads). Epilogue: bias + leaky + fused l2-norm;
// writes f32 out row (non-temporal), bf16 h row, len, and scale = dinv*len.
__global__ __launch_bounds__(256, 3) void transform_kernel(const unsigned short* __restrict__ h_bf,
                                                           const float* __restrict__ len_in,
                                                           const unsigned short* __restrict__ agg_bf,
                                                           const unsigned short* __restrict__ wfrag,
                                                           const float* __restrict__ b1,
                                                           const float* __restrict__ b2,
                                                           const float* __restrict__ dinv,
                                                           float* __restrict__ out_norm,
                                                           int ostride,
                                                           float* __restrict__ len_out,
                                                           float* __restrict__ scale_out,
                                                           unsigned short* __restrict__ hbf_out,
                                                           int n_nodes) {
    int lane = threadIdx.x & 63;
    int wave = (blockIdx.x * blockDim.x + threadIdx.x) >> 6;
    int n0 = wave * 16;
    if (n0 >= n_nodes) return;

    int r16 = lane & 15;   // A row / B,C col within tile
    int g   = lane >> 4;   // k-group

    // pre-converted B fragments: wfrag[(m*2+kt)*4+dt][lane]
    bf16x8 w1f[2][4], w2f[2][4];
#pragma unroll
    for (int kt = 0; kt < 2; ++kt) {
#pragma unroll
        for (int dt = 0; dt < 4; ++dt) {
            w1f[kt][dt] = *reinterpret_cast<const bf16x8*>(
                wfrag + (((size_t)(0 * 2 + kt) * 4 + dt) * 64 + lane) * 8);
            w2f[kt][dt] = *reinterpret_cast<const bf16x8*>(
                wfrag + (((size_t)(1 * 2 + kt) * 4 + dt) * 64 + lane) * 8);
        }
    }

    int row = n0 + r16;
    if (row >= n_nodes) row = n_nodes - 1;          // clamp for tail tile
    float lv = len_in ? len_in[row] : 1.0f;

    f32x4 acc1[4], acc2[4];
#pragma unroll
    for (int dt = 0; dt < 4; ++dt) {
        acc1[dt] = (f32x4){0.0f, 0.0f, 0.0f, 0.0f};
        acc2[dt] = (f32x4){0.0f, 0.0f, 0.0f, 0.0f};
    }

#pragma unroll
    for (int kt = 0; kt < 2; ++kt) {
        const unsigned short* ap = agg_bf + ((size_t)row << 6) + kt * 32 + 8 * g;
        const unsigned short* hp = h_bf + ((size_t)row << 6) + kt * 32 + 8 * g;
        bf16x8 af = *reinterpret_cast<const bf16x8*>(ap);
        bf16x8 h8 = *reinterpret_cast<const bf16x8*>(hp);
        bf16x8 mf;
#pragma unroll
        for (int j = 0; j < 8; ++j) {
            mf[j] = (short)f2bf(bf2f((unsigned short)af[j]) * bf2f((unsigned short)h8[j]) * lv);
        }
#pragma unroll
        for (int dt = 0; dt < 4; ++dt) {
            acc1[dt] = __builtin_amdgcn_mfma_f32_16x16x32_bf16(af, w1f[kt][dt], acc1[dt], 0, 0, 0);
            acc2[dt] = __builtin_amdgcn_mfma_f32_16x16x32_bf16(mf, w2f[kt][dt], acc2[dt], 0, 0, 0);
        }
    }

    float b1v[4], b2v[4];
#pragma unroll
    for (int dt = 0; dt < 4; ++dt) {
        b1v[dt] = b1[dt * 16 + r16];
        b2v[dt] = b2[dt * 16 + r16];
    }
    float v[4][4];  // [dt][reg]
#pragma unroll
    for (int dt = 0; dt < 4; ++dt) {
#pragma unroll
        for (int reg = 0; reg < 4; ++reg) {
            float x1 = acc1[dt][reg] + b1v[dt];
            float x2 = acc2[dt][reg] + b2v[dt];
            x1 = x1 > 0.0f ? x1 : LEAKY * x1;
            x2 = x2 > 0.0f ? x2 : LEAKY * x2;
            v[dt][reg] = x1 + x2;
        }
    }
#pragma unroll
    for (int reg = 0; reg < 4; ++reg) {
        float sq = v[0][reg] * v[0][reg] + v[1][reg] * v[1][reg] +
                   v[2][reg] * v[2][reg] + v[3][reg] * v[3][reg];
        sq += __shfl_xor(sq, 1, 64);
        sq += __shfl_xor(sq, 2, 64);
        sq += __shfl_xor(sq, 4, 64);
        sq += __shfl_xor(sq, 8, 64);
        float m = fmaxf(sq, 1e-12f);
        float inv = rsqrtf(m);
        int orow = n0 + 4 * g + reg;
        if (orow < n_nodes) {
#pragma unroll
            for (int dt = 0; dt < 4; ++dt) {
                float nv = v[dt][reg] * inv;
                __builtin_nontemporal_store(nv, &out_norm[(size_t)orow * ostride + dt * 16 + r16]);
                hbf_out[((size_t)orow << 6) + dt * 16 + r16] = f2bf(nv);
            }
            if (r16 == reg) {
                float ln = sqrtf(m);
                len_out[orow] = ln;
                scale_out[orow] = dinv[orow] * ln;   // fused scale kernel
            }
        }
    }
}

// ---------------------------------------------------------------- copy x -> slot 0 (+ bf16 table + deg zero)
__global__ __launch_bounds__(256) void copyx_zero_kernel(const float* __restrict__ x,
                                                         float* __restrict__ out,
                                                         unsigned short* __restrict__ x_bf,
                                                         int4* __restrict__ deg4, int n4,
                                                         int n_nodes, int nslots) {
    int t = blockIdx.x * 256 + threadIdx.x;
    if (t < n4) deg4[t] = (int4){0, 0, 0, 0};        // fused deg clear
    int total = n_nodes * 16;                 // 16 float4 per node row
    if (t >= total) return;
    int node = t >> 4;
    int j = t & 15;
    f32x4 v = reinterpret_cast<const f32x4*>(x)[(size_t)node * 16 + j];
    __builtin_nontemporal_store(v, &reinterpret_cast<f32x4*>(out)[(size_t)node * (nslots * 16) + j]);
    ushort4 b;
    b.x = f2bf(v.x); b.y = f2bf(v.y); b.z = f2bf(v.z); b.w = f2bf(v.w);
    reinterpret_cast<ushort4*>(x_bf)[(size_t)node * 16 + j] = b;
}

// ---------------------------------------------------------------- launch
extern "C" void kernel_launch(void* const* d_in, const int* in_sizes, int n_in,
                              void* d_out, int out_size, void* d_ws, size_t ws_size,
                              hipStream_t stream) {
    const float* x  = (const float*)d_in[0];
    const int*  edge = (const int*)d_in[1];
    const float* W1 = (const float*)d_in[2];
    const float* b1 = (const float*)d_in[3];
    const float* W2 = (const float*)d_in[4];
    const float* b2 = (const float*)d_in[5];

    const int N = in_sizes[0] / 64;
    const int E = in_sizes[1] / 2;
    const int K = in_sizes[2] / 4096;
    const int nslots = K + 1;
    const int ostride = nslots * 64;

    const int* row = edge;
    const int* col = edge + E;
    float* out = (float*)d_out;

    char* ws = (char*)d_ws;
    size_t off = 0;
    auto carve = [&](size_t bytes) -> void* {
        void* p = ws + off;
        off = (off + bytes + 255) & ~(size_t)255;
        return p;
    };
    const int n4 = (N + 3) / 4;
    int*   deg     = (int*)  carve((size_t)n4 * 16);
    int*   rowptr  = (int*)  carve((size_t)(N + 1) * 4);
    float* dinv    = (float*)carve((size_t)N * 4);
    float* scale   = (float*)carve((size_t)N * 4);
    float* len     = (float*)carve((size_t)N * 4);
    int*   rank    = (int*)  carve((size_t)E * 4);
    int*   cols_s  = (int*)  carve((size_t)E * 4);
    unsigned short* agg_bf = (unsigned short*)carve((size_t)N * 64 * 2);
    unsigned short* hbfA = (unsigned short*)carve((size_t)N * 64 * 2);
    unsigned short* hbfB = (unsigned short*)carve((size_t)N * 64 * 2);
    unsigned short* wfrag = (unsigned short*)carve((size_t)K * 2 * 2 * 4 * 64 * 8 * 2);
    int*   bsums   = (int*)  carve(2048 * 4);
    (void)ws_size;

    // copyx + deg-zero fused (must precede hist)
    copyx_zero_kernel<<<(N * 16 + 255) / 256, 256, 0, stream>>>(x, out, hbfA,
                                                                (int4*)deg, n4, N, nslots);

    const int wtotal = K * 2 * 2 * 4 * 64;
    wprep_kernel<<<(wtotal + 255) / 256, 256, 0, stream>>>(W1, W2, wfrag, wtotal);

    const int eblk4 = (E + 256 * 4 - 1) / (256 * 4);
    hist_rank_kernel<<<eblk4, 256, 0, stream>>>(row, E, deg, rank);

    const int nb = (N + 1 + SCAN_BS - 1) / SCAN_BS;
    bsum_kernel<<<nb, SCAN_BS, 0, stream>>>(deg, bsums, N);
    scan_bsums_kernel<<<1, 1024, 0, stream>>>(bsums, nb);
    rowptr_dinv_kernel<<<nb, SCAN_BS, 0, stream>>>(deg, bsums, rowptr, dinv, N);

    scatter_store_kernel<<<eblk4, 256, 0, stream>>>(row, col, rank, E, rowptr, cols_s);

    const int waves_needed = (N + 15) / 16;
    const int tblocks = (waves_needed + 3) / 4;

    unsigned short* hin = hbfA;
    unsigned short* hout = hbfB;
    for (int i = 0; i < K; ++i) {
        const float* len_in = (i == 0) ? nullptr : len;
        const float* sc = (i == 0) ? dinv : scale;   // scale written by prev transform
        aggregate_kernel<<<(N * 64 + 255) / 256, 256, 0, stream>>>(rowptr, cols_s, sc, dinv,
                                                                   hin, agg_bf, N);
        transform_kernel<<<tblocks, 256, 0, stream>>>(hin, len_in, agg_bf,
                                                      wfrag + (size_t)i * 2 * 2 * 4 * 64 * 8,
                                                      b1 + (size_t)i * 64,
                                                      b2 + (size_t)i * 64,
                                                      dinv,
                                                      out + (size_t)(i + 1) * 64,
                                                      ostride, len, scale, hout, N);
        unsigned short* tmp = hin; hin = hout; hout = tmp;
    }
}